// Round 10
// baseline (378.374 us; speedup 1.0000x reference)
//
#include <hip/hip_runtime.h>
#include <cstdint>
#include <cstddef>

#define D 64
#define CAPU 96
#define CAPI 128
#define OCAP 4096
#define GR 32       // rows per block in k_gcn_mlp
#define NPART 8     // XCD partitions (blockIdx & 7 -> XCD round-robin heuristic)
#define PSHIFT 11   // slot>>11 : 16384 slots / 8 partitions

typedef int v4i __attribute__((ext_vector_type(4)));

// ---------------- build compact slot maps ----------------
__global__ __launch_bounds__(256) void k_build_maps(const int* __restrict__ user_id,
                                                    const int* __restrict__ item_id,
                                                    int* __restrict__ map_u,
                                                    int* __restrict__ map_i, int B)
{
    int i = blockIdx.x * blockDim.x + threadIdx.x;
    if (i < B) {
        atomicCAS(&map_u[user_id[i]], -1, i);
        atomicCAS(&map_i[item_id[i]], -1, i);
    }
}

// ---------------- XCD-partitioned scatter ----------------
// part = blockIdx&7 (XCD-affine). Each partition scans ALL edges (nt loads, no
// L2 pollution) but writes only slots it owns -> counter/list lines stay
// XCD-local in L2, write-combined, drained once at kernel end. Kills the 16x
// write amplification of cross-XCD scattered 4B stores.
__global__ __launch_bounds__(256) void k_scatter(const int* __restrict__ edge_user,
                                                 const int* __restrict__ edge_item,
                                                 const int* __restrict__ map_u,
                                                 const int* __restrict__ map_i,
                                                 int* __restrict__ cntU,
                                                 int* __restrict__ cntI,
                                                 uint32_t* __restrict__ listU,
                                                 uint32_t* __restrict__ listI,
                                                 int* __restrict__ ovfCnt,
                                                 uint32_t* __restrict__ ovf, int E)
{
    const int part = blockIdx.x & (NPART - 1);
    const int nb = gridDim.x >> 3;       // blocks per partition
    const int bc = blockIdx.x >> 3;
    const int tid = threadIdx.x;
    const int nquads = E >> 2;

    for (int q = bc * 256 + tid; q < nquads; q += nb * 256) {
        int base = q * 4;
        v4i eu = __builtin_nontemporal_load((const v4i*)(edge_user + base));
        v4i ei = __builtin_nontemporal_load((const v4i*)(edge_item + base));
        #pragma unroll
        for (int k = 0; k < 4; ++k) {
            int u = eu[k], it = ei[k];
            int su = map_u[u];
            int si = map_i[it];
            if ((su >> PSHIFT) == part) {            // implies su >= 0
                int pos = atomicAdd(&cntU[su * 16], 1);
                if (pos < CAPU) listU[(size_t)su * CAPU + pos] = (uint32_t)it;
                else { int o = atomicAdd(ovfCnt, 1);
                       if (o < OCAP) ovf[o] = ((uint32_t)su << 17) | (uint32_t)it; }
            }
            if ((si >> PSHIFT) == part) {
                int pos = atomicAdd(&cntI[si * 16], 1);
                if (pos < CAPI) listI[(size_t)si * CAPI + pos] = (uint32_t)u;
                else { int o = atomicAdd(ovfCnt, 1);
                       if (o < OCAP) ovf[o] = 0x80000000u | ((uint32_t)si << 17) | (uint32_t)u; }
            }
        }
    }

    // tail (E % 4 != 0) — single block handles all partitions (E=2M -> empty)
    if (part == 0 && bc == 0) {
        for (int e = (nquads << 2) + tid; e < E; e += 256) {
            int u = edge_user[e], it = edge_item[e];
            int su = map_u[u], si = map_i[it];
            if (su >= 0) {
                int pos = atomicAdd(&cntU[su * 16], 1);
                if (pos < CAPU) listU[(size_t)su * CAPU + pos] = (uint32_t)it;
                else { int o = atomicAdd(ovfCnt, 1);
                       if (o < OCAP) ovf[o] = ((uint32_t)su << 17) | (uint32_t)it; }
            }
            if (si >= 0) {
                int pos = atomicAdd(&cntI[si * 16], 1);
                if (pos < CAPI) listI[(size_t)si * CAPI + pos] = (uint32_t)u;
                else { int o = atomicAdd(ovfCnt, 1);
                       if (o < OCAP) ovf[o] = 0x80000000u | ((uint32_t)si << 17) | (uint32_t)u; }
            }
        }
    }
}

// ---------------- gather-reduce + normalize: one 16-lane group per (side,slot) ----------------
__global__ __launch_bounds__(256) void k_gather(const uint32_t* __restrict__ listU,
                                                const uint32_t* __restrict__ listI,
                                                const int* __restrict__ cntU,
                                                const int* __restrict__ cntI,
                                                const float* __restrict__ user_table,
                                                const float* __restrict__ item_table,
                                                const int* __restrict__ ovfCnt,
                                                const uint32_t* __restrict__ ovf,
                                                float* __restrict__ aggIU,
                                                float* __restrict__ aggUI, int B)
{
    int gg = (blockIdx.x * blockDim.x + threadIdx.x) >> 4;
    if (gg >= 2 * B) return;
    int l16 = threadIdx.x & 15;
    int side = gg >= B;
    int slot = side ? gg - B : gg;

    int cnt = side ? cntI[slot * 16] : cntU[slot * 16];
    int caps = side ? CAPI : CAPU;
    int n = cnt < caps ? cnt : caps;
    const uint32_t* list = side ? (listI + (size_t)slot * CAPI)
                                : (listU + (size_t)slot * CAPU);
    const float4* table4 = (const float4*)(side ? user_table : item_table);

    float4 a0 = {0.f,0.f,0.f,0.f}, a1 = {0.f,0.f,0.f,0.f};
    float4 a2 = {0.f,0.f,0.f,0.f}, a3 = {0.f,0.f,0.f,0.f};
    int j = 0;
    for (; j + 4 <= n; j += 4) {
        int r0 = (int)list[j], r1 = (int)list[j+1], r2 = (int)list[j+2], r3 = (int)list[j+3];
        float4 v0 = table4[(size_t)r0 * 16 + l16];
        float4 v1 = table4[(size_t)r1 * 16 + l16];
        float4 v2 = table4[(size_t)r2 * 16 + l16];
        float4 v3 = table4[(size_t)r3 * 16 + l16];
        a0.x += v0.x; a0.y += v0.y; a0.z += v0.z; a0.w += v0.w;
        a1.x += v1.x; a1.y += v1.y; a1.z += v1.z; a1.w += v1.w;
        a2.x += v2.x; a2.y += v2.y; a2.z += v2.z; a2.w += v2.w;
        a3.x += v3.x; a3.y += v3.y; a3.z += v3.z; a3.w += v3.w;
    }
    for (; j < n; ++j) {
        int r0 = (int)list[j];
        float4 v0 = table4[(size_t)r0 * 16 + l16];
        a0.x += v0.x; a0.y += v0.y; a0.z += v0.z; a0.w += v0.w;
    }
    if (cnt > caps) {                 // statistically never taken
        int on = *ovfCnt; if (on > OCAP) on = OCAP;
        for (int k = 0; k < on; ++k) {
            uint32_t p = ovf[k];
            if ((int)(p >> 31) == side && (int)((p >> 17) & 0x3FFFu) == slot) {
                float4 v = table4[(size_t)(p & 0x1FFFFu) * 16 + l16];
                a0.x += v.x; a0.y += v.y; a0.z += v.z; a0.w += v.w;
            }
        }
    }
    float inv = 1.0f / ((float)cnt + 1.0f);      // deg = cnt + 1
    float4 acc = {(a0.x+a1.x+a2.x+a3.x) * inv, (a0.y+a1.y+a2.y+a3.y) * inv,
                  (a0.z+a1.z+a2.z+a3.z) * inv, (a0.w+a1.w+a2.w+a3.w) * inv};
    float4* agg4 = (float4*)(side ? aggUI : aggIU);
    agg4[(size_t)slot * 16 + l16] = acc;
}

// ---------------- fused GCN + MLP ----------------
__global__ __launch_bounds__(256) void k_gcn_mlp(const int* __restrict__ user_id,
                                                 const int* __restrict__ item_id,
                                                 const int* __restrict__ map_u,
                                                 const int* __restrict__ map_i,
                                                 const float* __restrict__ aggIU,
                                                 const float* __restrict__ aggUI,
                                                 const float* __restrict__ user_table,
                                                 const float* __restrict__ item_table,
                                                 const float* __restrict__ Wi,
                                                 const float* __restrict__ bi,
                                                 const float* __restrict__ Wu,
                                                 const float* __restrict__ bu,
                                                 const float* __restrict__ W1,
                                                 const float* __restrict__ b1,
                                                 const float* __restrict__ W2,
                                                 const float* __restrict__ b2,
                                                 const float* __restrict__ W3,
                                                 const float* __restrict__ b3,
                                                 const float* __restrict__ user_bias,
                                                 const float* __restrict__ item_bias,
                                                 float* __restrict__ out, int B)
{
    __shared__ float XgiL[GR][68];
    __shared__ float XguL[GR][68];
    __shared__ float Fbuf[2 * GR][68];   // ue rows 0-31, ie rows 32-63; later x1t[32][132]
    __shared__ float WB[8192];           // Wi/Wu (16KB) then W1 slices / W2 (32KB)
    __shared__ int sU[GR], sI[GR];
    int t = threadIdx.x;
    int row0 = blockIdx.x * GR;
    if (t < GR) { sU[t] = user_id[row0 + t]; sI[t] = item_id[row0 + t]; }
    __syncthreads();

    int txg = t & 15, tyg = t >> 4;      // gcn mapping: cols txg+16c, rows 2*tyg+r
    // ---- GCN item-side: XgiL = relu(aggIU[map_u[sU]] @ Wi + bi) ----
    {
        const float4* agg4 = (const float4*)aggIU;
        #pragma unroll
        for (int q = 0; q < 2; ++q) {
            int idx = t * 2 + q; int r = idx >> 4, l16 = idx & 15;
            int slot = map_u[sU[r]];
            ((float4*)&Fbuf[r][0])[l16] = agg4[(size_t)slot * 16 + l16];
        }
        const float4* wg = (const float4*)Wi;
        float4* d = (float4*)WB;
        #pragma unroll
        for (int q = 0; q < 4; ++q) d[t + q * 256] = wg[t + q * 256];
    }
    __syncthreads();
    {
        float acc[2][4] = {};
        for (int k = 0; k < 64; ++k) {
            float a0 = Fbuf[2 * tyg][k], a1 = Fbuf[2 * tyg + 1][k];
            #pragma unroll
            for (int c = 0; c < 4; ++c) {
                float w = WB[k * 64 + txg + 16 * c];
                acc[0][c] = fmaf(a0, w, acc[0][c]);
                acc[1][c] = fmaf(a1, w, acc[1][c]);
            }
        }
        #pragma unroll
        for (int r = 0; r < 2; ++r)
            #pragma unroll
            for (int c = 0; c < 4; ++c)
                XgiL[2 * tyg + r][txg + 16 * c] = fmaxf(acc[r][c] + bi[txg + 16 * c], 0.f);
    }
    __syncthreads();
    // ---- GCN user-side: XguL = relu(aggUI[map_i[sI]] @ Wu + bu) ----
    {
        const float4* agg4 = (const float4*)aggUI;
        #pragma unroll
        for (int q = 0; q < 2; ++q) {
            int idx = t * 2 + q; int r = idx >> 4, l16 = idx & 15;
            int slot = map_i[sI[r]];
            ((float4*)&Fbuf[r][0])[l16] = agg4[(size_t)slot * 16 + l16];
        }
        const float4* wg = (const float4*)Wu;
        float4* d = (float4*)WB;
        #pragma unroll
        for (int q = 0; q < 4; ++q) d[t + q * 256] = wg[t + q * 256];
    }
    __syncthreads();
    {
        float acc[2][4] = {};
        for (int k = 0; k < 64; ++k) {
            float a0 = Fbuf[2 * tyg][k], a1 = Fbuf[2 * tyg + 1][k];
            #pragma unroll
            for (int c = 0; c < 4; ++c) {
                float w = WB[k * 64 + txg + 16 * c];
                acc[0][c] = fmaf(a0, w, acc[0][c]);
                acc[1][c] = fmaf(a1, w, acc[1][c]);
            }
        }
        #pragma unroll
        for (int r = 0; r < 2; ++r)
            #pragma unroll
            for (int c = 0; c < 4; ++c)
                XguL[2 * tyg + r][txg + 16 * c] = fmaxf(acc[r][c] + bu[txg + 16 * c], 0.f);
    }
    __syncthreads();   // Fbuf free for ue/ie; WB free for W1

    // ---- stage ue (rows 0-31) and ie (rows 32-63) ----
    #pragma unroll
    for (int q = 0; q < 2; ++q) {
        int idx = t * 2 + q; int r = idx >> 4, l16 = idx & 15;
        ((float4*)&Fbuf[r][0])[l16] = ((const float4*)user_table)[(size_t)sU[r] * 16 + l16];
        ((float4*)&Fbuf[GR + r][0])[l16] = ((const float4*)item_table)[(size_t)sI[r] * 16 + l16];
    }

    // ---- MLP layer 1: 4 phases over W1 K-slices ----
    int tx1 = t & 31, ty1 = t >> 5;      // cols tx1+32c (128), rows 4*ty1+r (32)
    float acc1[4][4] = {};
    for (int j = 0; j < 4; ++j) {
        {
            const float4* w4 = (const float4*)W1 + (size_t)j * 2048;
            float4* d = (float4*)WB;
            #pragma unroll
            for (int q = 0; q < 8; ++q) d[t + q * 256] = w4[t + q * 256];
        }
        __syncthreads();
        const float (*FA)[68] = (j < 2) ? (const float (*)[68])&Fbuf[0] : (const float (*)[68])XguL;
        const float (*FB)[68] = ((j & 1) == 0) ? (const float (*)[68])&Fbuf[GR] : (const float (*)[68])XgiL;
        for (int k = 0; k < 64; ++k) {
            float a[4], b[4];
            #pragma unroll
            for (int r = 0; r < 4; ++r) a[r] = FA[4 * ty1 + r][k] * FB[4 * ty1 + r][k];
            #pragma unroll
            for (int c = 0; c < 4; ++c) b[c] = WB[k * 128 + tx1 + 32 * c];
            #pragma unroll
            for (int r = 0; r < 4; ++r)
                #pragma unroll
                for (int c = 0; c < 4; ++c)
                    acc1[r][c] = fmaf(a[r], b[c], acc1[r][c]);
        }
        __syncthreads();
    }

    // ---- x1 tile -> LDS (overlay Fbuf as [32][132]); stage W2 ----
    float* x1t = &Fbuf[0][0];
    #pragma unroll
    for (int r = 0; r < 4; ++r)
        #pragma unroll
        for (int c = 0; c < 4; ++c) {
            int col = tx1 + 32 * c;
            x1t[(4 * ty1 + r) * 132 + col] = tanhf(acc1[r][c] + b1[col]);
        }
    {
        const float4* w4 = (const float4*)W2;
        float4* d = (float4*)WB;
        #pragma unroll
        for (int q = 0; q < 8; ++q) d[t + q * 256] = w4[t + q * 256];
    }
    __syncthreads();

    // ---- layer 2 + head ----
    int tx2 = t & 15, ty2 = t >> 4;      // cols tx2+16c (64), rows 2*ty2+r (32)
    float acc2[2][4] = {};
    for (int k = 0; k < 128; ++k) {
        float a0 = x1t[(2 * ty2) * 132 + k];
        float a1 = x1t[(2 * ty2 + 1) * 132 + k];
        #pragma unroll
        for (int c = 0; c < 4; ++c) {
            float w = WB[k * 64 + tx2 + 16 * c];
            acc2[0][c] = fmaf(a0, w, acc2[0][c]);
            acc2[1][c] = fmaf(a1, w, acc2[1][c]);
        }
    }
    float b3v = b3[0];
    #pragma unroll
    for (int r = 0; r < 2; ++r) {
        int lr = 2 * ty2 + r;
        float p = 0.f;
        #pragma unroll
        for (int c = 0; c < 4; ++c) {
            int col = tx2 + 16 * c;
            p += tanhf(acc2[r][c] + b2[col]) * W3[col];
        }
        p += __shfl_xor(p, 1);
        p += __shfl_xor(p, 2);
        p += __shfl_xor(p, 4);
        p += __shfl_xor(p, 8);
        if (tx2 == 0)
            out[row0 + lr] = p + b3v + user_bias[sU[lr]] + item_bias[sI[lr]];
    }
}

extern "C" void kernel_launch(void* const* d_in, const int* in_sizes, int n_in,
                              void* d_out, int out_size, void* d_ws, size_t ws_size,
                              hipStream_t stream)
{
    const float* user_table = (const float*)d_in[0];
    const float* item_table = (const float*)d_in[1];
    const float* Wu = (const float*)d_in[2];
    const float* bu = (const float*)d_in[3];
    const float* Wi = (const float*)d_in[4];
    const float* bi = (const float*)d_in[5];
    const float* W1 = (const float*)d_in[6];
    const float* b1 = (const float*)d_in[7];
    const float* W2 = (const float*)d_in[8];
    const float* b2 = (const float*)d_in[9];
    const float* W3 = (const float*)d_in[10];
    const float* b3 = (const float*)d_in[11];
    const float* user_bias = (const float*)d_in[12];
    const float* item_bias = (const float*)d_in[13];
    const int* user_id = (const int*)d_in[14];
    const int* item_id = (const int*)d_in[15];
    const int* edge_user = (const int*)d_in[16];
    const int* edge_item = (const int*)d_in[17];

    const int N_USER = in_sizes[0] / D;
    const int N_ITEM = in_sizes[1] / D;
    const int B = in_sizes[14];
    const int E = in_sizes[16];

    // ---- workspace layout (bytes) ----
    char* ws = (char*)d_ws;
    size_t off = 0;
    const size_t aggIU_off = off; off += (size_t)B * D * 4;
    const size_t aggUI_off = off; off += (size_t)B * D * 4;
    const size_t mapu_off  = off; off += (size_t)N_USER * 4;
    const size_t mapi_off  = off; off += (size_t)N_ITEM * 4;
    const size_t cntU_off  = off; off += (size_t)B * 16 * 4;
    const size_t cntI_off  = off; off += (size_t)B * 16 * 4;
    const size_t ovfc_off  = off; off += 256;
    const size_t ovf_off   = off; off += (size_t)OCAP * 4;
    const size_t listU_off = off; off += (size_t)B * CAPU * 4;
    const size_t listI_off = off; off += (size_t)B * CAPI * 4;

    float* aggIU = (float*)(ws + aggIU_off);
    float* aggUI = (float*)(ws + aggUI_off);
    int*   map_u = (int*)(ws + mapu_off);
    int*   map_i = (int*)(ws + mapi_off);
    int*   cntU  = (int*)(ws + cntU_off);
    int*   cntI  = (int*)(ws + cntI_off);
    int*   ovfCnt = (int*)(ws + ovfc_off);
    uint32_t* ovf = (uint32_t*)(ws + ovf_off);
    uint32_t* listU = (uint32_t*)(ws + listU_off);
    uint32_t* listI = (uint32_t*)(ws + listI_off);

    hipMemsetAsync(ws + mapu_off, 0xFF, (size_t)(N_USER + N_ITEM) * 4, stream);         // maps = -1
    hipMemsetAsync(ws + cntU_off, 0, (size_t)B * 16 * 4 * 2 + 256 + OCAP * 4, stream);  // cnt+ovf = 0

    k_build_maps<<<(B + 255) / 256, 256, 0, stream>>>(user_id, item_id, map_u, map_i, B);

    // 2048 blocks = 256 per partition x 8 partitions (blockIdx&7 -> XCD)
    k_scatter<<<2048, 256, 0, stream>>>(edge_user, edge_item, map_u, map_i,
                                        cntU, cntI, listU, listI, ovfCnt, ovf, E);

    k_gather<<<(2 * B) / 16, 256, 0, stream>>>(listU, listI, cntU, cntI,
                                               user_table, item_table, ovfCnt, ovf,
                                               aggIU, aggUI, B);

    k_gcn_mlp<<<B / GR, 256, 0, stream>>>(user_id, item_id, map_u, map_i,
                                          aggIU, aggUI, user_table, item_table,
                                          Wi, bi, Wu, bu, W1, b1, W2, b2, W3, b3,
                                          user_bias, item_bias, (float*)d_out, B);
}

// Round 13
// 231.954 us; speedup vs baseline: 1.6312x; 1.6312x over previous
//
#include <hip/hip_runtime.h>
#include <cstdint>
#include <cstddef>

#define D 64
#define CAPU 96
#define CAPI 128
#define OCAP 4096
#define GR 32   // rows per block in k_gcn_mlp

// ---------------- build compact slot maps ----------------
__global__ __launch_bounds__(256) void k_build_maps(const int* __restrict__ user_id,
                                                    const int* __restrict__ item_id,
                                                    int* __restrict__ map_u,
                                                    int* __restrict__ map_i, int B)
{
    int i = blockIdx.x * blockDim.x + threadIdx.x;
    if (i < B) {
        atomicCAS(&map_u[user_id[i]], -1, i);
        atomicCAS(&map_i[item_id[i]], -1, i);
    }
}

// ---------------- scatter hit edges into per-slot CSR lists ----------------
// Round-9 form (best measured): 2 edges/thread, max resident waves.
// Scatter is bounded by scattered-RMW/store line movement (~1.1 TB/s eff):
// ILP (r7), wave count (r9), and XCD partitioning (r10) all failed to beat it.
__global__ __launch_bounds__(256) void k_scatter(const int* __restrict__ edge_user,
                                                 const int* __restrict__ edge_item,
                                                 const int* __restrict__ map_u,
                                                 const int* __restrict__ map_i,
                                                 int* __restrict__ cntU,
                                                 int* __restrict__ cntI,
                                                 uint32_t* __restrict__ listU,
                                                 uint32_t* __restrict__ listI,
                                                 int* __restrict__ ovfCnt,
                                                 uint32_t* __restrict__ ovf, int E)
{
    int t = blockIdx.x * blockDim.x + threadIdx.x;
    int base = t * 2;
    if (base >= E) return;

    int u0, u1 = -1, i0, i1 = 0;
    if (base + 2 <= E) {
        int2 eu = *(const int2*)(edge_user + base);
        int2 ei = *(const int2*)(edge_item + base);
        u0 = eu.x; u1 = eu.y; i0 = ei.x; i1 = ei.y;
    } else {
        u0 = edge_user[base]; i0 = edge_item[base];
    }

    int su0 = map_u[u0];
    int si0 = map_i[i0];
    int su1 = (u1 >= 0) ? map_u[u1] : -1;
    int si1 = (u1 >= 0) ? map_i[i1] : -1;

    if (su0 >= 0) {
        int pos = atomicAdd(&cntU[su0 * 16], 1);
        if (pos < CAPU) listU[(size_t)su0 * CAPU + pos] = (uint32_t)i0;
        else { int o = atomicAdd(ovfCnt, 1);
               if (o < OCAP) ovf[o] = ((uint32_t)su0 << 17) | (uint32_t)i0; }
    }
    if (si0 >= 0) {
        int pos = atomicAdd(&cntI[si0 * 16], 1);
        if (pos < CAPI) listI[(size_t)si0 * CAPI + pos] = (uint32_t)u0;
        else { int o = atomicAdd(ovfCnt, 1);
               if (o < OCAP) ovf[o] = 0x80000000u | ((uint32_t)si0 << 17) | (uint32_t)u0; }
    }
    if (su1 >= 0) {
        int pos = atomicAdd(&cntU[su1 * 16], 1);
        if (pos < CAPU) listU[(size_t)su1 * CAPU + pos] = (uint32_t)i1;
        else { int o = atomicAdd(ovfCnt, 1);
               if (o < OCAP) ovf[o] = ((uint32_t)su1 << 17) | (uint32_t)i1; }
    }
    if (si1 >= 0) {
        int pos = atomicAdd(&cntI[si1 * 16], 1);
        if (pos < CAPI) listI[(size_t)si1 * CAPI + pos] = (uint32_t)u1;
        else { int o = atomicAdd(ovfCnt, 1);
               if (o < OCAP) ovf[o] = 0x80000000u | ((uint32_t)si1 << 17) | (uint32_t)u1; }
    }
}

// ---------------- gather-reduce + normalize: one 16-lane group per (side,slot) ----------------
// 8-wide unroll: 8 independent 256B row-gathers in flight per group.
__global__ __launch_bounds__(256) void k_gather(const uint32_t* __restrict__ listU,
                                                const uint32_t* __restrict__ listI,
                                                const int* __restrict__ cntU,
                                                const int* __restrict__ cntI,
                                                const float* __restrict__ user_table,
                                                const float* __restrict__ item_table,
                                                const int* __restrict__ ovfCnt,
                                                const uint32_t* __restrict__ ovf,
                                                float* __restrict__ aggIU,
                                                float* __restrict__ aggUI, int B)
{
    int gg = (blockIdx.x * blockDim.x + threadIdx.x) >> 4;
    if (gg >= 2 * B) return;
    int l16 = threadIdx.x & 15;
    int side = gg >= B;
    int slot = side ? gg - B : gg;

    int cnt = side ? cntI[slot * 16] : cntU[slot * 16];
    int caps = side ? CAPI : CAPU;
    int n = cnt < caps ? cnt : caps;
    const uint32_t* list = side ? (listI + (size_t)slot * CAPI)
                                : (listU + (size_t)slot * CAPU);
    const float4* table4 = (const float4*)(side ? user_table : item_table);

    float4 a0 = {0.f,0.f,0.f,0.f}, a1 = {0.f,0.f,0.f,0.f};
    float4 a2 = {0.f,0.f,0.f,0.f}, a3 = {0.f,0.f,0.f,0.f};
    int j = 0;
    for (; j + 8 <= n; j += 8) {
        int r0 = (int)list[j],   r1 = (int)list[j+1], r2 = (int)list[j+2], r3 = (int)list[j+3];
        int r4 = (int)list[j+4], r5 = (int)list[j+5], r6 = (int)list[j+6], r7 = (int)list[j+7];
        float4 v0 = table4[(size_t)r0 * 16 + l16];
        float4 v1 = table4[(size_t)r1 * 16 + l16];
        float4 v2 = table4[(size_t)r2 * 16 + l16];
        float4 v3 = table4[(size_t)r3 * 16 + l16];
        float4 v4 = table4[(size_t)r4 * 16 + l16];
        float4 v5 = table4[(size_t)r5 * 16 + l16];
        float4 v6 = table4[(size_t)r6 * 16 + l16];
        float4 v7 = table4[(size_t)r7 * 16 + l16];
        a0.x += v0.x; a0.y += v0.y; a0.z += v0.z; a0.w += v0.w;
        a1.x += v1.x; a1.y += v1.y; a1.z += v1.z; a1.w += v1.w;
        a2.x += v2.x; a2.y += v2.y; a2.z += v2.z; a2.w += v2.w;
        a3.x += v3.x; a3.y += v3.y; a3.z += v3.z; a3.w += v3.w;
        a0.x += v4.x; a0.y += v4.y; a0.z += v4.z; a0.w += v4.w;
        a1.x += v5.x; a1.y += v5.y; a1.z += v5.z; a1.w += v5.w;
        a2.x += v6.x; a2.y += v6.y; a2.z += v6.z; a2.w += v6.w;
        a3.x += v7.x; a3.y += v7.y; a3.z += v7.z; a3.w += v7.w;
    }
    for (; j < n; ++j) {
        int r0 = (int)list[j];
        float4 v0 = table4[(size_t)r0 * 16 + l16];
        a0.x += v0.x; a0.y += v0.y; a0.z += v0.z; a0.w += v0.w;
    }
    if (cnt > caps) {                 // statistically never taken
        int on = *ovfCnt; if (on > OCAP) on = OCAP;
        for (int k = 0; k < on; ++k) {
            uint32_t p = ovf[k];
            if ((int)(p >> 31) == side && (int)((p >> 17) & 0x3FFFu) == slot) {
                float4 v = table4[(size_t)(p & 0x1FFFFu) * 16 + l16];
                a0.x += v.x; a0.y += v.y; a0.z += v.z; a0.w += v.w;
            }
        }
    }
    float inv = 1.0f / ((float)cnt + 1.0f);      // deg = cnt + 1
    float4 acc = {(a0.x+a1.x+a2.x+a3.x) * inv, (a0.y+a1.y+a2.y+a3.y) * inv,
                  (a0.z+a1.z+a2.z+a3.z) * inv, (a0.w+a1.w+a2.w+a3.w) * inv};
    float4* agg4 = (float4*)(side ? aggUI : aggIU);
    agg4[(size_t)slot * 16 + l16] = acc;
}

// ---------------- fused GCN + MLP ----------------
__global__ __launch_bounds__(256) void k_gcn_mlp(const int* __restrict__ user_id,
                                                 const int* __restrict__ item_id,
                                                 const int* __restrict__ map_u,
                                                 const int* __restrict__ map_i,
                                                 const float* __restrict__ aggIU,
                                                 const float* __restrict__ aggUI,
                                                 const float* __restrict__ user_table,
                                                 const float* __restrict__ item_table,
                                                 const float* __restrict__ Wi,
                                                 const float* __restrict__ bi,
                                                 const float* __restrict__ Wu,
                                                 const float* __restrict__ bu,
                                                 const float* __restrict__ W1,
                                                 const float* __restrict__ b1,
                                                 const float* __restrict__ W2,
                                                 const float* __restrict__ b2,
                                                 const float* __restrict__ W3,
                                                 const float* __restrict__ b3,
                                                 const float* __restrict__ user_bias,
                                                 const float* __restrict__ item_bias,
                                                 float* __restrict__ out, int B)
{
    __shared__ float XgiL[GR][68];
    __shared__ float XguL[GR][68];
    __shared__ float Fbuf[2 * GR][68];   // ue rows 0-31, ie rows 32-63; later x1t[32][132]
    __shared__ float WB[8192];           // Wi/Wu (16KB) then W1 slices / W2 (32KB)
    __shared__ int sU[GR], sI[GR];
    int t = threadIdx.x;
    int row0 = blockIdx.x * GR;
    if (t < GR) { sU[t] = user_id[row0 + t]; sI[t] = item_id[row0 + t]; }
    __syncthreads();

    int txg = t & 15, tyg = t >> 4;      // gcn mapping: cols txg+16c, rows 2*tyg+r
    // ---- GCN item-side: XgiL = relu(aggIU[map_u[sU]] @ Wi + bi) ----
    {
        const float4* agg4 = (const float4*)aggIU;
        #pragma unroll
        for (int q = 0; q < 2; ++q) {
            int idx = t * 2 + q; int r = idx >> 4, l16 = idx & 15;
            int slot = map_u[sU[r]];
            ((float4*)&Fbuf[r][0])[l16] = agg4[(size_t)slot * 16 + l16];
        }
        const float4* wg = (const float4*)Wi;
        float4* d = (float4*)WB;
        #pragma unroll
        for (int q = 0; q < 4; ++q) d[t + q * 256] = wg[t + q * 256];
    }
    __syncthreads();
    {
        float acc[2][4] = {};
        for (int k = 0; k < 64; ++k) {
            float a0 = Fbuf[2 * tyg][k], a1 = Fbuf[2 * tyg + 1][k];
            #pragma unroll
            for (int c = 0; c < 4; ++c) {
                float w = WB[k * 64 + txg + 16 * c];
                acc[0][c] = fmaf(a0, w, acc[0][c]);
                acc[1][c] = fmaf(a1, w, acc[1][c]);
            }
        }
        #pragma unroll
        for (int r = 0; r < 2; ++r)
            #pragma unroll
            for (int c = 0; c < 4; ++c)
                XgiL[2 * tyg + r][txg + 16 * c] = fmaxf(acc[r][c] + bi[txg + 16 * c], 0.f);
    }
    __syncthreads();
    // ---- GCN user-side: XguL = relu(aggUI[map_i[sI]] @ Wu + bu) ----
    {
        const float4* agg4 = (const float4*)aggUI;
        #pragma unroll
        for (int q = 0; q < 2; ++q) {
            int idx = t * 2 + q; int r = idx >> 4, l16 = idx & 15;
            int slot = map_i[sI[r]];
            ((float4*)&Fbuf[r][0])[l16] = agg4[(size_t)slot * 16 + l16];
        }
        const float4* wg = (const float4*)Wu;
        float4* d = (float4*)WB;
        #pragma unroll
        for (int q = 0; q < 4; ++q) d[t + q * 256] = wg[t + q * 256];
    }
    __syncthreads();
    {
        float acc[2][4] = {};
        for (int k = 0; k < 64; ++k) {
            float a0 = Fbuf[2 * tyg][k], a1 = Fbuf[2 * tyg + 1][k];
            #pragma unroll
            for (int c = 0; c < 4; ++c) {
                float w = WB[k * 64 + txg + 16 * c];
                acc[0][c] = fmaf(a0, w, acc[0][c]);
                acc[1][c] = fmaf(a1, w, acc[1][c]);
            }
        }
        #pragma unroll
        for (int r = 0; r < 2; ++r)
            #pragma unroll
            for (int c = 0; c < 4; ++c)
                XguL[2 * tyg + r][txg + 16 * c] = fmaxf(acc[r][c] + bu[txg + 16 * c], 0.f);
    }
    __syncthreads();   // Fbuf free for ue/ie; WB free for W1

    // ---- stage ue (rows 0-31) and ie (rows 32-63) ----
    #pragma unroll
    for (int q = 0; q < 2; ++q) {
        int idx = t * 2 + q; int r = idx >> 4, l16 = idx & 15;
        ((float4*)&Fbuf[r][0])[l16] = ((const float4*)user_table)[(size_t)sU[r] * 16 + l16];
        ((float4*)&Fbuf[GR + r][0])[l16] = ((const float4*)item_table)[(size_t)sI[r] * 16 + l16];
    }

    // ---- MLP layer 1: 4 phases over W1 K-slices ----
    int tx1 = t & 31, ty1 = t >> 5;      // cols tx1+32c (128), rows 4*ty1+r (32)
    float acc1[4][4] = {};
    for (int j = 0; j < 4; ++j) {
        {
            const float4* w4 = (const float4*)W1 + (size_t)j * 2048;
            float4* d = (float4*)WB;
            #pragma unroll
            for (int q = 0; q < 8; ++q) d[t + q * 256] = w4[t + q * 256];
        }
        __syncthreads();
        const float (*FA)[68] = (j < 2) ? (const float (*)[68])&Fbuf[0] : (const float (*)[68])XguL;
        const float (*FB)[68] = ((j & 1) == 0) ? (const float (*)[68])&Fbuf[GR] : (const float (*)[68])XgiL;
        for (int k = 0; k < 64; ++k) {
            float a[4], b[4];
            #pragma unroll
            for (int r = 0; r < 4; ++r) a[r] = FA[4 * ty1 + r][k] * FB[4 * ty1 + r][k];
            #pragma unroll
            for (int c = 0; c < 4; ++c) b[c] = WB[k * 128 + tx1 + 32 * c];
            #pragma unroll
            for (int r = 0; r < 4; ++r)
                #pragma unroll
                for (int c = 0; c < 4; ++c)
                    acc1[r][c] = fmaf(a[r], b[c], acc1[r][c]);
        }
        __syncthreads();
    }

    // ---- x1 tile -> LDS (overlay Fbuf as [32][132]); stage W2 ----
    float* x1t = &Fbuf[0][0];
    #pragma unroll
    for (int r = 0; r < 4; ++r)
        #pragma unroll
        for (int c = 0; c < 4; ++c) {
            int col = tx1 + 32 * c;
            x1t[(4 * ty1 + r) * 132 + col] = tanhf(acc1[r][c] + b1[col]);
        }
    {
        const float4* w4 = (const float4*)W2;
        float4* d = (float4*)WB;
        #pragma unroll
        for (int q = 0; q < 8; ++q) d[t + q * 256] = w4[t + q * 256];
    }
    __syncthreads();

    // ---- layer 2 + head ----
    int tx2 = t & 15, ty2 = t >> 4;      // cols tx2+16c (64), rows 2*ty2+r (32)
    float acc2[2][4] = {};
    for (int k = 0; k < 128; ++k) {
        float a0 = x1t[(2 * ty2) * 132 + k];
        float a1 = x1t[(2 * ty2 + 1) * 132 + k];
        #pragma unroll
        for (int c = 0; c < 4; ++c) {
            float w = WB[k * 64 + tx2 + 16 * c];
            acc2[0][c] = fmaf(a0, w, acc2[0][c]);
            acc2[1][c] = fmaf(a1, w, acc2[1][c]);
        }
    }
    float b3v = b3[0];
    #pragma unroll
    for (int r = 0; r < 2; ++r) {
        int lr = 2 * ty2 + r;
        float p = 0.f;
        #pragma unroll
        for (int c = 0; c < 4; ++c) {
            int col = tx2 + 16 * c;
            p += tanhf(acc2[r][c] + b2[col]) * W3[col];
        }
        p += __shfl_xor(p, 1);
        p += __shfl_xor(p, 2);
        p += __shfl_xor(p, 4);
        p += __shfl_xor(p, 8);
        if (tx2 == 0)
            out[row0 + lr] = p + b3v + user_bias[sU[lr]] + item_bias[sI[lr]];
    }
}

extern "C" void kernel_launch(void* const* d_in, const int* in_sizes, int n_in,
                              void* d_out, int out_size, void* d_ws, size_t ws_size,
                              hipStream_t stream)
{
    const float* user_table = (const float*)d_in[0];
    const float* item_table = (const float*)d_in[1];
    const float* Wu = (const float*)d_in[2];
    const float* bu = (const float*)d_in[3];
    const float* Wi = (const float*)d_in[4];
    const float* bi = (const float*)d_in[5];
    const float* W1 = (const float*)d_in[6];
    const float* b1 = (const float*)d_in[7];
    const float* W2 = (const float*)d_in[8];
    const float* b2 = (const float*)d_in[9];
    const float* W3 = (const float*)d_in[10];
    const float* b3 = (const float*)d_in[11];
    const float* user_bias = (const float*)d_in[12];
    const float* item_bias = (const float*)d_in[13];
    const int* user_id = (const int*)d_in[14];
    const int* item_id = (const int*)d_in[15];
    const int* edge_user = (const int*)d_in[16];
    const int* edge_item = (const int*)d_in[17];

    const int N_USER = in_sizes[0] / D;
    const int N_ITEM = in_sizes[1] / D;
    const int B = in_sizes[14];
    const int E = in_sizes[16];

    // ---- workspace layout (bytes) ----
    char* ws = (char*)d_ws;
    size_t off = 0;
    const size_t aggIU_off = off; off += (size_t)B * D * 4;
    const size_t aggUI_off = off; off += (size_t)B * D * 4;
    const size_t mapu_off  = off; off += (size_t)N_USER * 4;
    const size_t mapi_off  = off; off += (size_t)N_ITEM * 4;
    const size_t cntU_off  = off; off += (size_t)B * 16 * 4;
    const size_t cntI_off  = off; off += (size_t)B * 16 * 4;
    const size_t ovfc_off  = off; off += 256;
    const size_t ovf_off   = off; off += (size_t)OCAP * 4;
    const size_t listU_off = off; off += (size_t)B * CAPU * 4;
    const size_t listI_off = off; off += (size_t)B * CAPI * 4;

    float* aggIU = (float*)(ws + aggIU_off);
    float* aggUI = (float*)(ws + aggUI_off);
    int*   map_u = (int*)(ws + mapu_off);
    int*   map_i = (int*)(ws + mapi_off);
    int*   cntU  = (int*)(ws + cntU_off);
    int*   cntI  = (int*)(ws + cntI_off);
    int*   ovfCnt = (int*)(ws + ovfc_off);
    uint32_t* ovf = (uint32_t*)(ws + ovf_off);
    uint32_t* listU = (uint32_t*)(ws + listU_off);
    uint32_t* listI = (uint32_t*)(ws + listI_off);

    hipMemsetAsync(ws + mapu_off, 0xFF, (size_t)(N_USER + N_ITEM) * 4, stream);         // maps = -1
    hipMemsetAsync(ws + cntU_off, 0, (size_t)B * 16 * 4 * 2 + 256 + OCAP * 4, stream);  // cnt+ovf = 0

    k_build_maps<<<(B + 255) / 256, 256, 0, stream>>>(user_id, item_id, map_u, map_i, B);

    k_scatter<<<(E / 2 + 255) / 256, 256, 0, stream>>>(edge_user, edge_item, map_u, map_i,
                                                       cntU, cntI, listU, listI, ovfCnt, ovf, E);

    k_gather<<<(2 * B) / 16, 256, 0, stream>>>(listU, listI, cntU, cntI,
                                               user_table, item_table, ovfCnt, ovf,
                                               aggIU, aggUI, B);

    k_gcn_mlp<<<B / GR, 256, 0, stream>>>(user_id, item_id, map_u, map_i,
                                          aggIU, aggUI, user_table, item_table,
                                          Wi, bi, Wu, bu, W1, b1, W2, b2, W3, b3,
                                          user_bias, item_bias, (float*)d_out, B);
}